// Round 5
// baseline (219.105 us; speedup 1.0000x reference)
//
#include <hip/hip_runtime.h>
#include <math.h>

#define E_   1024
#define H_   16
#define B_   4
#define T_   1024
#define LAMBDA_INIT 0.783605766532f
// D^-1/2 * log2(e): Q pre-scaled so softmax exp becomes raw v_exp_f32 (2^x)
#define SCALE_QL2E 0.25503486f

typedef short s16x8 __attribute__((ext_vector_type(8)));
typedef float f32x4 __attribute__((ext_vector_type(4)));

// ushort offset of 16B chunk c in a 64-ushort (128B) swizzled row r
#define SWZ(c, r) ((((c) ^ ((r) & 7)) * 8))

// float -> bf16 raw bits, round-to-nearest-even
__device__ inline ushort f2bf(float x) {
    unsigned u = __builtin_bit_cast(unsigned, x);
    u += 0x7fffu + ((u >> 16) & 1u);
    return (ushort)(u >> 16);
}

// pack two floats -> 2x bf16 in one uint (lo, hi)
__device__ inline uint f2bf2(float lo, float hi) {
#if __has_builtin(__builtin_amdgcn_cvt_pk_bf16_f32)
    typedef __bf16 bf16x2_t __attribute__((ext_vector_type(2)));
    bf16x2_t r = __builtin_amdgcn_cvt_pk_bf16_f32(lo, hi);
    return __builtin_bit_cast(uint, r);
#else
    uint ul = __builtin_bit_cast(uint, lo);
    uint uh = __builtin_bit_cast(uint, hi);
    ul += 0x7fffu + ((ul >> 16) & 1u);
    uh += 0x7fffu + ((uh >> 16) & 1u);
    return __builtin_amdgcn_perm(uh, ul, 0x07060302u);
#endif
}

// raw 2^x (v_exp_f32, no preceding v_mul)
__device__ inline float exp2fast(float x) {
#if __has_builtin(__builtin_amdgcn_exp2f)
    return __builtin_amdgcn_exp2f(x);
#else
    return exp2f(x);
#endif
}

// async global->LDS, 16 bytes per lane; LDS dest = base + lane*16
__device__ inline void gl_lds16(const ushort* g, ushort* l) {
    __builtin_amdgcn_global_load_lds((const __attribute__((address_space(1))) void*)g,
                                     (__attribute__((address_space(3))) void*)l,
                                     16, 0, 0);
}

// ---------------------------------------------------------------------------
// prep: fp32->bf16 casts for x + 4 weights, plus lambda scalar (one launch).
// ---------------------------------------------------------------------------
__global__ __launch_bounds__(256) void prep(
    const float* __restrict__ x,  const float* __restrict__ Wq,
    const float* __restrict__ Wk, const float* __restrict__ Wv,
    const float* __restrict__ Wo,
    const float* __restrict__ lq1, const float* __restrict__ lk1,
    const float* __restrict__ lq2, const float* __restrict__ lk2,
    ushort* __restrict__ xb, ushort* __restrict__ Wqb, ushort* __restrict__ Wkb,
    ushort* __restrict__ Wvb, ushort* __restrict__ Wob, float* __restrict__ lamp)
{
    const int blk = blockIdx.x;
    const int tid = threadIdx.x;
    if (blk >= 4096) {
        if (tid < 64) {
            float p1 = 0.f, p2 = 0.f;
            if (tid < 32) { p1 = lq1[tid] * lk1[tid]; p2 = lq2[tid] * lk2[tid]; }
            #pragma unroll
            for (int off = 32; off; off >>= 1) {
                p1 += __shfl_xor(p1, off);
                p2 += __shfl_xor(p2, off);
            }
            if (tid == 0) lamp[0] = expf(p1) - expf(p2) + LAMBDA_INIT;
        }
        return;
    }
    const float* in;
    ushort* out;
    int base;
    if (blk < 2048) { in = x; out = xb; base = blk; }
    else {
        int t = blk - 2048, w = t >> 9;
        base = t & 511;
        in  = w == 0 ? Wq  : (w == 1 ? Wk  : (w == 2 ? Wv  : Wo));
        out = w == 0 ? Wqb : (w == 1 ? Wkb : (w == 2 ? Wvb : Wob));
    }
    int i = (base * 256 + tid) * 8;
    float4 a = *(const float4*)&in[i];
    float4 b = *(const float4*)&in[i + 4];
    union { ushort u[8]; uint4 v; } o;
    o.u[0] = f2bf(a.x); o.u[1] = f2bf(a.y); o.u[2] = f2bf(a.z); o.u[3] = f2bf(a.w);
    o.u[4] = f2bf(b.x); o.u[5] = f2bf(b.y); o.u[6] = f2bf(b.z); o.u[7] = f2bf(b.w);
    *(uint4*)&out[i] = o.v;
}

// ---------------------------------------------------------------------------
// Fused QKV projection GEMM.
// R11 (kept from R4, verified win): BK=64 2-barrier loop, sequential K-slices
// (fragment liveness 32 VGPR), no min-waves bound. 128B LDS rows XOR-swizzled
// (pre-swizzled source + swizzled read). Q/K regions accumulate TRANSPOSED
// (acc = mfma(b, a)); V written transposed into Vt[b][e][t].
// ---------------------------------------------------------------------------
__global__ __launch_bounds__(256) void gemm_qkv(
    const ushort* __restrict__ Xb, const ushort* __restrict__ Wqb,
    const ushort* __restrict__ Wkb, const ushort* __restrict__ Wvb,
    ushort* __restrict__ QK, ushort* __restrict__ Vt)
{
    __shared__ __align__(16) ushort As[128 * 64];   // 16 KB
    __shared__ __align__(16) ushort Ws[128 * 64];   // 16 KB
    const int tid = threadIdx.x;
    const int wave = tid >> 6, lane = tid & 63;
    const int l15 = lane & 15, quad = lane >> 4;
    const int bm = blockIdx.y * 128;
    const int bng = blockIdx.x * 128;
    const int region = bng >> 10;
    const ushort* W = region == 0 ? Wqb : (region == 1 ? Wkb : Wvb);
    const float scale = region == 0 ? SCALE_QL2E : 1.0f;
    const int wn = bng & 1023;
    const int lr  = lane >> 3;                 // row within 8-row staging group
    const int jsw = ((lane & 7) ^ lr) * 8;     // pre-swizzled global col chunk
    // swizzled read offsets within a row (row ≡ l15 mod 8)
    const int roff0 = l15 * 64 + SWZ(quad, l15);       // k-slice 0 (cols 0..31)
    const int roff1 = l15 * 64 + SWZ(4 + quad, l15);   // k-slice 1 (cols 32..63)

    f32x4 acc[4][4] = {};
    const int wr = wave >> 1, wc = wave & 1;

    for (int k0 = 0; k0 < 1024; k0 += 64) {
        #pragma unroll
        for (int p = 0; p < 4; ++p) {
            int r = wave * 32 + p * 8;
            gl_lds16(&Xb[(size_t)(bm + r + lr) * 1024 + k0 + jsw], &As[r * 64]);
            gl_lds16(&W [(size_t)(wn + r + lr) * 1024 + k0 + jsw], &Ws[r * 64]);
        }
        __syncthreads();
        #pragma unroll
        for (int ks = 0; ks < 2; ++ks) {
            const int roff = ks ? roff1 : roff0;
            s16x8 a[4], b[4];
            #pragma unroll
            for (int i = 0; i < 4; ++i)
                a[i] = *(const s16x8*)&As[(wr * 64 + i * 16) * 64 + roff];
            #pragma unroll
            for (int j = 0; j < 4; ++j)
                b[j] = *(const s16x8*)&Ws[(wc * 64 + j * 16) * 64 + roff];
            if (region < 2) {
                #pragma unroll
                for (int i = 0; i < 4; ++i)
                    #pragma unroll
                    for (int j = 0; j < 4; ++j)
                        acc[i][j] = __builtin_amdgcn_mfma_f32_16x16x32_bf16(b[j], a[i], acc[i][j], 0, 0, 0);
            } else {
                #pragma unroll
                for (int i = 0; i < 4; ++i)
                    #pragma unroll
                    for (int j = 0; j < 4; ++j)
                        acc[i][j] = __builtin_amdgcn_mfma_f32_16x16x32_bf16(a[i], b[j], acc[i][j], 0, 0, 0);
            }
        }
        __syncthreads();
    }

    if (region < 2) {
        // lane holds: X-row = l15 (tile i), 4 consecutive cols quad*4+r (tile j)
        #pragma unroll
        for (int i = 0; i < 4; ++i) {
            int row = bm + wr * 64 + i * 16 + l15;
            #pragma unroll
            for (int j = 0; j < 4; ++j) {
                int col = region * 1024 + wn + wc * 64 + j * 16 + quad * 4;
                ushort4 o;
                o.x = f2bf(acc[i][j][0] * scale); o.y = f2bf(acc[i][j][1] * scale);
                o.z = f2bf(acc[i][j][2] * scale); o.w = f2bf(acc[i][j][3] * scale);
                *(ushort4*)&QK[(size_t)row * 2048 + col] = o;
            }
        }
    } else {
        // V: write transposed, Vt[b][e][t]; lane holds 4 consecutive t per (i,j)
        const int bb = bm >> 10;
        const int t0 = (bm & 1023) + wr * 64 + quad * 4;
        #pragma unroll
        for (int i = 0; i < 4; ++i)
            #pragma unroll
            for (int j = 0; j < 4; ++j) {
                int e = wn + wc * 64 + j * 16 + l15;
                ushort4 o;
                o.x = f2bf(acc[i][j][0]); o.y = f2bf(acc[i][j][1]);
                o.z = f2bf(acc[i][j][2]); o.w = f2bf(acc[i][j][3]);
                *(ushort4*)&Vt[((size_t)bb * E_ + e) * T_ + t0 + i * 16] = o;
            }
    }
}

// ---------------------------------------------------------------------------
// Output GEMM: R11 BK=64 sequential-slice structure (kept).
// C_f32[4096][1024] = Ab @ Wo.T (BM=64, BN=128).
// ---------------------------------------------------------------------------
__global__ __launch_bounds__(256) void gemm_out(
    const ushort* __restrict__ Ab, const ushort* __restrict__ Wob,
    float* __restrict__ C)
{
    __shared__ __align__(16) ushort As[64 * 64];    // 8 KB
    __shared__ __align__(16) ushort Ws[128 * 64];   // 16 KB
    const int tid = threadIdx.x;
    const int wave = tid >> 6, lane = tid & 63;
    const int l15 = lane & 15, quad = lane >> 4;
    const int bm = blockIdx.y * 64;
    const int bn = blockIdx.x * 128;
    const int lr  = lane >> 3;
    const int jsw = ((lane & 7) ^ lr) * 8;
    const int roff0 = l15 * 64 + SWZ(quad, l15);
    const int roff1 = l15 * 64 + SWZ(4 + quad, l15);

    f32x4 acc[2][4] = {};
    const int wr = wave >> 1, wc = wave & 1;

    for (int k0 = 0; k0 < 1024; k0 += 64) {
        #pragma unroll
        for (int p = 0; p < 2; ++p) {
            int r = wave * 16 + p * 8;
            gl_lds16(&Ab[(size_t)(bm + r + lr) * 1024 + k0 + jsw], &As[r * 64]);
        }
        #pragma unroll
        for (int p = 0; p < 4; ++p) {
            int r = wave * 32 + p * 8;
            gl_lds16(&Wob[(size_t)(bn + r + lr) * 1024 + k0 + jsw], &Ws[r * 64]);
        }
        __syncthreads();
        #pragma unroll
        for (int ks = 0; ks < 2; ++ks) {
            const int roff = ks ? roff1 : roff0;
            s16x8 a[2], b[4];
            #pragma unroll
            for (int i = 0; i < 2; ++i)
                a[i] = *(const s16x8*)&As[(wr * 32 + i * 16) * 64 + roff];
            #pragma unroll
            for (int j = 0; j < 4; ++j)
                b[j] = *(const s16x8*)&Ws[(wc * 64 + j * 16) * 64 + roff];
            #pragma unroll
            for (int i = 0; i < 2; ++i)
                #pragma unroll
                for (int j = 0; j < 4; ++j)
                    acc[i][j] = __builtin_amdgcn_mfma_f32_16x16x32_bf16(b[j], a[i], acc[i][j], 0, 0, 0);
        }
        __syncthreads();
    }

    // lane holds: A-row = l15 (tile i), 4 consecutive cols quad*4+r (tile j)
    #pragma unroll
    for (int i = 0; i < 2; ++i) {
        int row = bm + wr * 32 + i * 16 + l15;
        #pragma unroll
        for (int j = 0; j < 4; ++j) {
            int col = bn + wc * 64 + j * 16 + quad * 4;
            float4 o;
            o.x = acc[i][j][0]; o.y = acc[i][j][1];
            o.z = acc[i][j][2]; o.w = acc[i][j][3];
            *(float4*)&C[(size_t)row * 1024 + col] = o;
        }
    }
}

// ---------------------------------------------------------------------------
// Differential attention v7: R4 counters showed the LDS pipe is the binding
// resource (~67% of wall; K/V fragment reads are identical across all 4
// waves -> 4x duplicated traffic). m169 lesson: V is L2-resident (128 KB per
// (b,h), reused by 16 blocks) -> DROP Vts staging, read the 8 va fragments
// per kt straight from global (VMEM pipe idle at 6% HBM). K stays LDS-staged
// (ping-pong + 1 barrier/kt unchanged). Staging guarded (kt != 15) so the
// next-tile address is affine. LDS 40 -> 24 KB; LDS traffic/wave/kt -33%.
// ---------------------------------------------------------------------------
__global__ __launch_bounds__(256, 4) void diff_attn(
    const ushort* __restrict__ QK, const ushort* __restrict__ Vt,
    const float* __restrict__ g, const float* __restrict__ lamp,
    ushort* __restrict__ O)
{
    __shared__ __align__(16) ushort Ks[2][4096];   // 16 KB
    __shared__ __align__(16) ushort Pt[4][1024];   //  8 KB

    const int tid  = threadIdx.x;
    const int lane = tid & 63;
    const int wave = tid >> 6;
    const int l15  = lane & 15;
    const int quad = lane >> 4;

    const int blk = blockIdx.x;
    const int bh = blk & 63;           // same-head blocks share blk%8 -> same XCD
    const int qt = blk >> 6;
    const int b  = bh >> 4;
    const int h  = bh & 15;
    const int q0 = qt * 64;
    const int hoff = h * 64;
    const size_t rowbase = (size_t)b * T_;

    const ushort* Qg = QK;
    const ushort* Kg = QK + 1024;
    const size_t vtbase = ((size_t)b * E_ + hoff) * T_;

    const int lr  = lane >> 3;
    const int jsw = ((lane & 7) ^ lr) * 8;

    const size_t qrow = (rowbase + q0 + wave * 16 + l15) * 2048 + hoff;
    s16x8 aq0 = *(const s16x8*)&Qg[qrow + quad * 8];
    s16x8 aq1 = *(const s16x8*)&Qg[qrow + 32 + quad * 8];

    const int kaoff0 = l15 * 64 + SWZ(quad,     l15);
    const int kaoff1 = l15 * 64 + SWZ(4 + quad, l15);
    ushort* myPt = &Pt[wave][0];

    const f32x4 zf = {0.f, 0.f, 0.f, 0.f};
    f32x4 o0[4] = {zf, zf, zf, zf};
    f32x4 o1[4] = {zf, zf, zf, zf};
    float lsum0 = 0.f, lsum1 = 0.f;

    #pragma unroll
    for (int p = 0; p < 2; ++p) {
        int r = wave * 16 + p * 8;
        gl_lds16(&Kg[(rowbase + r + lr) * 2048 + hoff + jsw], &Ks[0][r * 64]);
    }
    __syncthreads();

    for (int kt = 0; kt < 16; ++kt) {
        const int cur = kt & 1;
        const int nxt = cur ^ 1;
        if (kt != 15) {
            const int ktn = kt + 1;
            #pragma unroll
            for (int p = 0; p < 2; ++p) {
                int r = wave * 16 + p * 8;
                gl_lds16(&Kg[(rowbase + ktn * 64 + r + lr) * 2048 + hoff + jsw],
                         &Ks[nxt][r * 64]);
            }
        }

        // V fragments direct from global (L2-resident), issued before QK^T so
        // L2 latency hides under QK + softmax. Same values Vts carried before:
        // e-row = hoff + jt*16 + l15, t = kt*64 + h2*32 + quad*8.
        s16x8 va[4][2];
        #pragma unroll
        for (int jt = 0; jt < 4; ++jt) {
            const ushort* vrow = &Vt[vtbase + (size_t)(jt * 16 + l15) * T_ + kt * 64 + quad * 8];
            va[jt][0] = *(const s16x8*)(vrow);
            va[jt][1] = *(const s16x8*)(vrow + 32);
        }

        // ---- comp 0 ----
        {
            f32x4 S[4];
            #pragma unroll
            for (int jk = 0; jk < 4; ++jk) {
                s16x8 ka = *(const s16x8*)&Ks[cur][jk * 1024 + kaoff0];
                S[jk] = __builtin_amdgcn_mfma_f32_16x16x32_bf16(ka, aq0, zf, 0, 0, 0);
            }
            #pragma unroll
            for (int jk = 0; jk < 4; ++jk) {
                float e0 = exp2fast(S[jk][0]), e1 = exp2fast(S[jk][1]);
                float e2 = exp2fast(S[jk][2]), e3 = exp2fast(S[jk][3]);
                lsum0 += (e0 + e1) + (e2 + e3);
                uint2 pk; pk.x = f2bf2(e0, e1); pk.y = f2bf2(e2, e3);
                *(uint2*)&myPt[l15 * 64 + SWZ(2 * jk + (quad >> 1), l15) + (quad & 1) * 4] = pk;
            }
            #pragma unroll
            for (int h2 = 0; h2 < 2; ++h2) {
                s16x8 pf = *(const s16x8*)&myPt[h2 ? kaoff1 : kaoff0];
                #pragma unroll
                for (int jt = 0; jt < 4; ++jt)
                    o0[jt] = __builtin_amdgcn_mfma_f32_16x16x32_bf16(va[jt][h2], pf, o0[jt], 0, 0, 0);
            }
        }
        // ---- comp 1 ----
        {
            f32x4 S[4];
            #pragma unroll
            for (int jk = 0; jk < 4; ++jk) {
                s16x8 ka = *(const s16x8*)&Ks[cur][jk * 1024 + kaoff1];
                S[jk] = __builtin_amdgcn_mfma_f32_16x16x32_bf16(ka, aq1, zf, 0, 0, 0);
            }
            #pragma unroll
            for (int jk = 0; jk < 4; ++jk) {
                float e0 = exp2fast(S[jk][0]), e1 = exp2fast(S[jk][1]);
                float e2 = exp2fast(S[jk][2]), e3 = exp2fast(S[jk][3]);
                lsum1 += (e0 + e1) + (e2 + e3);
                uint2 pk; pk.x = f2bf2(e0, e1); pk.y = f2bf2(e2, e3);
                *(uint2*)&myPt[l15 * 64 + SWZ(2 * jk + (quad >> 1), l15) + (quad & 1) * 4] = pk;
            }
            #pragma unroll
            for (int h2 = 0; h2 < 2; ++h2) {
                s16x8 pf = *(const s16x8*)&myPt[h2 ? kaoff1 : kaoff0];
                #pragma unroll
                for (int jt = 0; jt < 4; ++jt)
                    o1[jt] = __builtin_amdgcn_mfma_f32_16x16x32_bf16(va[jt][h2], pf, o1[jt], 0, 0, 0);
            }
        }
        __syncthreads();
    }

    lsum0 += __shfl_xor(lsum0, 16); lsum0 += __shfl_xor(lsum0, 32);
    lsum1 += __shfl_xor(lsum1, 16); lsum1 += __shfl_xor(lsum1, 32);

    const float lam = lamp[0];
    const float fin = 1.f - LAMBDA_INIT;
    float i0 = 1.f / lsum0;
    float i1 = lam / lsum1;
    float val[4][4];
    float ssq = 0.f;
    #pragma unroll
    for (int jt = 0; jt < 4; ++jt)
        #pragma unroll
        for (int r = 0; r < 4; ++r) {
            float v = o0[jt][r] * i0 - o1[jt][r] * i1;
            val[jt][r] = v;
            ssq += v * v;
        }
    ssq += __shfl_xor(ssq, 16);
    ssq += __shfl_xor(ssq, 32);
    float sc = rsqrtf(ssq * (1.f / 64.f) + 1e-5f) * fin;
    size_t rowoff = (rowbase + q0 + wave * 16 + l15) * 1024 + hoff;
    #pragma unroll
    for (int jt = 0; jt < 4; ++jt) {
        float4 gv = *(const float4*)&g[jt * 16 + quad * 4];
        uint p01 = f2bf2(val[jt][0] * sc * gv.x, val[jt][1] * sc * gv.y);
        uint p23 = f2bf2(val[jt][2] * sc * gv.z, val[jt][3] * sc * gv.w);
        *(uint*)&O[rowoff + jt * 16 + quad * 4 + 0] = p01;
        *(uint*)&O[rowoff + jt * 16 + quad * 4 + 2] = p23;
    }
}

// ---------------------------------------------------------------------------
extern "C" void kernel_launch(void* const* d_in, const int* in_sizes, int n_in,
                              void* d_out, int out_size, void* d_ws, size_t ws_size,
                              hipStream_t stream)
{
    const float* x   = (const float*)d_in[0];
    const float* Wq  = (const float*)d_in[1];
    const float* Wk  = (const float*)d_in[2];
    const float* Wv  = (const float*)d_in[3];
    const float* Wo  = (const float*)d_in[4];
    const float* lq1 = (const float*)d_in[5];
    const float* lk1 = (const float*)d_in[6];
    const float* lq2 = (const float*)d_in[7];
    const float* lk2 = (const float*)d_in[8];
    const float* g   = (const float*)d_in[9];
    float* out = (float*)d_out;

    const int M = B_ * T_;                 // 4096
    const size_t ME = (size_t)M * E_;      // 4M elems
    const size_t EE = (size_t)E_ * E_;     // 1M elems
    ushort* xb  = (ushort*)d_ws;           // x bf16; later reused as Ab
    ushort* Wqb = xb  + ME;
    ushort* Wkb = Wqb + EE;
    ushort* Wvb = Wkb + EE;
    ushort* Wob = Wvb + EE;
    ushort* QK  = Wob + EE;                // [4096][2048] bf16
    ushort* Vtb = QK + (size_t)M * 2048;   // [4][1024][1024] bf16 (e-major)
    float*  lamp = (float*)(Vtb + ME);
    ushort* Ab  = xb;                      // aliases xb (dead after gemm_qkv)

    prep<<<4097, 256, 0, stream>>>(x, Wq, Wk, Wv, Wo, lq1, lk1, lq2, lk2,
                                   xb, Wqb, Wkb, Wvb, Wob, lamp);
    gemm_qkv<<<dim3(24, 32), 256, 0, stream>>>(xb, Wqb, Wkb, Wvb, QK, Vtb);
    diff_attn<<<B_ * H_ * (T_ / 64), 256, 0, stream>>>(QK, Vtb, g, lamp, Ab);
    gemm_out<<<dim3(8, 64), 256, 0, stream>>>(Ab, Wob, out);
}

// Round 7
// 193.690 us; speedup vs baseline: 1.1312x; 1.1312x over previous
//
#include <hip/hip_runtime.h>
#include <math.h>

#define E_   1024
#define H_   16
#define B_   4
#define T_   1024
#define LAMBDA_INIT 0.783605766532f
// D^-1/2 * log2(e): Q pre-scaled so softmax exp becomes raw v_exp_f32 (2^x)
#define SCALE_QL2E 0.25503486f

typedef short s16x8 __attribute__((ext_vector_type(8)));
typedef float f32x4 __attribute__((ext_vector_type(4)));

// ushort offset of 16B chunk c in a 64-ushort (128B) swizzled row r
#define SWZ(c, r) ((((c) ^ ((r) & 7)) * 8))

// float -> bf16 raw bits, round-to-nearest-even
__device__ inline ushort f2bf(float x) {
    unsigned u = __builtin_bit_cast(unsigned, x);
    u += 0x7fffu + ((u >> 16) & 1u);
    return (ushort)(u >> 16);
}

// pack two floats -> 2x bf16 in one uint (lo, hi)
__device__ inline uint f2bf2(float lo, float hi) {
#if __has_builtin(__builtin_amdgcn_cvt_pk_bf16_f32)
    typedef __bf16 bf16x2_t __attribute__((ext_vector_type(2)));
    bf16x2_t r = __builtin_amdgcn_cvt_pk_bf16_f32(lo, hi);
    return __builtin_bit_cast(uint, r);
#else
    uint ul = __builtin_bit_cast(uint, lo);
    uint uh = __builtin_bit_cast(uint, hi);
    ul += 0x7fffu + ((ul >> 16) & 1u);
    uh += 0x7fffu + ((uh >> 16) & 1u);
    return __builtin_amdgcn_perm(uh, ul, 0x07060302u);
#endif
}

// raw 2^x (v_exp_f32, no preceding v_mul)
__device__ inline float exp2fast(float x) {
#if __has_builtin(__builtin_amdgcn_exp2f)
    return __builtin_amdgcn_exp2f(x);
#else
    return exp2f(x);
#endif
}

// async global->LDS, 16 bytes per lane; LDS dest = base + lane*16
__device__ inline void gl_lds16(const ushort* g, ushort* l) {
    __builtin_amdgcn_global_load_lds((const __attribute__((address_space(1))) void*)g,
                                     (__attribute__((address_space(3))) void*)l,
                                     16, 0, 0);
}

// ---------------------------------------------------------------------------
// prep: fp32->bf16 casts for x + 4 weights, plus lambda scalar (one launch).
// ---------------------------------------------------------------------------
__global__ __launch_bounds__(256) void prep(
    const float* __restrict__ x,  const float* __restrict__ Wq,
    const float* __restrict__ Wk, const float* __restrict__ Wv,
    const float* __restrict__ Wo,
    const float* __restrict__ lq1, const float* __restrict__ lk1,
    const float* __restrict__ lq2, const float* __restrict__ lk2,
    ushort* __restrict__ xb, ushort* __restrict__ Wqb, ushort* __restrict__ Wkb,
    ushort* __restrict__ Wvb, ushort* __restrict__ Wob, float* __restrict__ lamp)
{
    const int blk = blockIdx.x;
    const int tid = threadIdx.x;
    if (blk >= 4096) {
        if (tid < 64) {
            float p1 = 0.f, p2 = 0.f;
            if (tid < 32) { p1 = lq1[tid] * lk1[tid]; p2 = lq2[tid] * lk2[tid]; }
            #pragma unroll
            for (int off = 32; off; off >>= 1) {
                p1 += __shfl_xor(p1, off);
                p2 += __shfl_xor(p2, off);
            }
            if (tid == 0) lamp[0] = expf(p1) - expf(p2) + LAMBDA_INIT;
        }
        return;
    }
    const float* in;
    ushort* out;
    int base;
    if (blk < 2048) { in = x; out = xb; base = blk; }
    else {
        int t = blk - 2048, w = t >> 9;
        base = t & 511;
        in  = w == 0 ? Wq  : (w == 1 ? Wk  : (w == 2 ? Wv  : Wo));
        out = w == 0 ? Wqb : (w == 1 ? Wkb : (w == 2 ? Wvb : Wob));
    }
    int i = (base * 256 + tid) * 8;
    float4 a = *(const float4*)&in[i];
    float4 b = *(const float4*)&in[i + 4];
    union { ushort u[8]; uint4 v; } o;
    o.u[0] = f2bf(a.x); o.u[1] = f2bf(a.y); o.u[2] = f2bf(a.z); o.u[3] = f2bf(a.w);
    o.u[4] = f2bf(b.x); o.u[5] = f2bf(b.y); o.u[6] = f2bf(b.z); o.u[7] = f2bf(b.w);
    *(uint4*)&out[i] = o.v;
}

// ---------------------------------------------------------------------------
// Fused QKV projection GEMM.
// R11 (verified win, kept): BK=64 2-barrier loop, sequential K-slices
// (fragment liveness 32 VGPR), no min-waves bound. 128B LDS rows XOR-swizzled
// (pre-swizzled source + swizzled read). Q/K regions accumulate TRANSPOSED
// (acc = mfma(b, a)); V written transposed into Vt[b][e][t].
// ---------------------------------------------------------------------------
__global__ __launch_bounds__(256) void gemm_qkv(
    const ushort* __restrict__ Xb, const ushort* __restrict__ Wqb,
    const ushort* __restrict__ Wkb, const ushort* __restrict__ Wvb,
    ushort* __restrict__ QK, ushort* __restrict__ Vt)
{
    __shared__ __align__(16) ushort As[128 * 64];   // 16 KB
    __shared__ __align__(16) ushort Ws[128 * 64];   // 16 KB
    const int tid = threadIdx.x;
    const int wave = tid >> 6, lane = tid & 63;
    const int l15 = lane & 15, quad = lane >> 4;
    const int bm = blockIdx.y * 128;
    const int bng = blockIdx.x * 128;
    const int region = bng >> 10;
    const ushort* W = region == 0 ? Wqb : (region == 1 ? Wkb : Wvb);
    const float scale = region == 0 ? SCALE_QL2E : 1.0f;
    const int wn = bng & 1023;
    const int lr  = lane >> 3;                 // row within 8-row staging group
    const int jsw = ((lane & 7) ^ lr) * 8;     // pre-swizzled global col chunk
    // swizzled read offsets within a row (row ≡ l15 mod 8)
    const int roff0 = l15 * 64 + SWZ(quad, l15);       // k-slice 0 (cols 0..31)
    const int roff1 = l15 * 64 + SWZ(4 + quad, l15);   // k-slice 1 (cols 32..63)

    f32x4 acc[4][4] = {};
    const int wr = wave >> 1, wc = wave & 1;

    for (int k0 = 0; k0 < 1024; k0 += 64) {
        #pragma unroll
        for (int p = 0; p < 4; ++p) {
            int r = wave * 32 + p * 8;
            gl_lds16(&Xb[(size_t)(bm + r + lr) * 1024 + k0 + jsw], &As[r * 64]);
            gl_lds16(&W [(size_t)(wn + r + lr) * 1024 + k0 + jsw], &Ws[r * 64]);
        }
        __syncthreads();
        #pragma unroll
        for (int ks = 0; ks < 2; ++ks) {
            const int roff = ks ? roff1 : roff0;
            s16x8 a[4], b[4];
            #pragma unroll
            for (int i = 0; i < 4; ++i)
                a[i] = *(const s16x8*)&As[(wr * 64 + i * 16) * 64 + roff];
            #pragma unroll
            for (int j = 0; j < 4; ++j)
                b[j] = *(const s16x8*)&Ws[(wc * 64 + j * 16) * 64 + roff];
            if (region < 2) {
                #pragma unroll
                for (int i = 0; i < 4; ++i)
                    #pragma unroll
                    for (int j = 0; j < 4; ++j)
                        acc[i][j] = __builtin_amdgcn_mfma_f32_16x16x32_bf16(b[j], a[i], acc[i][j], 0, 0, 0);
            } else {
                #pragma unroll
                for (int i = 0; i < 4; ++i)
                    #pragma unroll
                    for (int j = 0; j < 4; ++j)
                        acc[i][j] = __builtin_amdgcn_mfma_f32_16x16x32_bf16(a[i], b[j], acc[i][j], 0, 0, 0);
            }
        }
        __syncthreads();
    }

    if (region < 2) {
        // lane holds: X-row = l15 (tile i), 4 consecutive cols quad*4+r (tile j)
        #pragma unroll
        for (int i = 0; i < 4; ++i) {
            int row = bm + wr * 64 + i * 16 + l15;
            #pragma unroll
            for (int j = 0; j < 4; ++j) {
                int col = region * 1024 + wn + wc * 64 + j * 16 + quad * 4;
                ushort4 o;
                o.x = f2bf(acc[i][j][0] * scale); o.y = f2bf(acc[i][j][1] * scale);
                o.z = f2bf(acc[i][j][2] * scale); o.w = f2bf(acc[i][j][3] * scale);
                *(ushort4*)&QK[(size_t)row * 2048 + col] = o;
            }
        }
    } else {
        // V: write transposed, Vt[b][e][t]; lane holds 4 consecutive t per (i,j)
        const int bb = bm >> 10;
        const int t0 = (bm & 1023) + wr * 64 + quad * 4;
        #pragma unroll
        for (int i = 0; i < 4; ++i)
            #pragma unroll
            for (int j = 0; j < 4; ++j) {
                int e = wn + wc * 64 + j * 16 + l15;
                ushort4 o;
                o.x = f2bf(acc[i][j][0]); o.y = f2bf(acc[i][j][1]);
                o.z = f2bf(acc[i][j][2]); o.w = f2bf(acc[i][j][3]);
                *(ushort4*)&Vt[((size_t)bb * E_ + e) * T_ + t0 + i * 16] = o;
            }
    }
}

// ---------------------------------------------------------------------------
// Output GEMM. R13: BN 128 -> 64 (grid (16,64) = 1024 blocks = 4 blocks/CU,
// up from 2). The 2-barrier family is latency-bound on the vmcnt(0) barrier
// drain; blocks/CU is the TLP that hides it (m97's 912 TF point had 4/CU).
// Per wave: 32x32 tile, acc[2][2]. W-fetch requests double but Wob is 2 MB
// (L2/L3-resident) -> no HBM delta. LDS 24 -> 16 KB.
// ---------------------------------------------------------------------------
__global__ __launch_bounds__(256) void gemm_out(
    const ushort* __restrict__ Ab, const ushort* __restrict__ Wob,
    float* __restrict__ C)
{
    __shared__ __align__(16) ushort As[64 * 64];    // 8 KB
    __shared__ __align__(16) ushort Ws[64 * 64];    // 8 KB
    const int tid = threadIdx.x;
    const int wave = tid >> 6, lane = tid & 63;
    const int l15 = lane & 15, quad = lane >> 4;
    const int bm = blockIdx.y * 64;
    const int bn = blockIdx.x * 64;
    const int lr  = lane >> 3;
    const int jsw = ((lane & 7) ^ lr) * 8;
    const int roff0 = l15 * 64 + SWZ(quad, l15);
    const int roff1 = l15 * 64 + SWZ(4 + quad, l15);

    f32x4 acc[2][2] = {};
    const int wr = wave >> 1, wc = wave & 1;

    for (int k0 = 0; k0 < 1024; k0 += 64) {
        #pragma unroll
        for (int p = 0; p < 2; ++p) {
            int r = wave * 16 + p * 8;
            gl_lds16(&Ab[(size_t)(bm + r + lr) * 1024 + k0 + jsw], &As[r * 64]);
            gl_lds16(&Wob[(size_t)(bn + r + lr) * 1024 + k0 + jsw], &Ws[r * 64]);
        }
        __syncthreads();
        #pragma unroll
        for (int ks = 0; ks < 2; ++ks) {
            const int roff = ks ? roff1 : roff0;
            s16x8 a[2], b[2];
            #pragma unroll
            for (int i = 0; i < 2; ++i)
                a[i] = *(const s16x8*)&As[(wr * 32 + i * 16) * 64 + roff];
            #pragma unroll
            for (int j = 0; j < 2; ++j)
                b[j] = *(const s16x8*)&Ws[(wc * 32 + j * 16) * 64 + roff];
            #pragma unroll
            for (int i = 0; i < 2; ++i)
                #pragma unroll
                for (int j = 0; j < 2; ++j)
                    acc[i][j] = __builtin_amdgcn_mfma_f32_16x16x32_bf16(b[j], a[i], acc[i][j], 0, 0, 0);
        }
        __syncthreads();
    }

    // lane holds: A-row = l15 (tile i), 4 consecutive cols quad*4+r (tile j)
    #pragma unroll
    for (int i = 0; i < 2; ++i) {
        int row = bm + wr * 32 + i * 16 + l15;
        #pragma unroll
        for (int j = 0; j < 2; ++j) {
            int col = bn + wc * 32 + j * 16 + quad * 4;
            float4 o;
            o.x = acc[i][j][0]; o.y = acc[i][j][1];
            o.z = acc[i][j][2]; o.w = acc[i][j][3];
            *(float4*)&C[(size_t)row * 1024 + col] = o;
        }
    }
}

// ---------------------------------------------------------------------------
// Differential attention v6 — REVERTED to the R4-exact version (52.4 µs
// measured). R5 (V-from-global) regressed to 78 µs (latency-bound scatter);
// R6 (permlane in-register P redistribution) failed correctness (permlane16
// orientation differs from model). Pt LDS round-trip retained.
// ---------------------------------------------------------------------------
__global__ __launch_bounds__(256, 4) void diff_attn(
    const ushort* __restrict__ QK, const ushort* __restrict__ Vt,
    const float* __restrict__ g, const float* __restrict__ lamp,
    ushort* __restrict__ O)
{
    __shared__ __align__(16) ushort Ks[2][4096];   // 16 KB
    __shared__ __align__(16) ushort Vts[2][4096];  // 16 KB
    __shared__ __align__(16) ushort Pt[4][1024];   //  8 KB

    const int tid  = threadIdx.x;
    const int lane = tid & 63;
    const int wave = tid >> 6;
    const int l15  = lane & 15;
    const int quad = lane >> 4;

    const int blk = blockIdx.x;
    const int bh = blk & 63;           // same-head blocks share blk%8 -> same XCD
    const int qt = blk >> 6;
    const int b  = bh >> 4;
    const int h  = bh & 15;
    const int q0 = qt * 64;
    const int hoff = h * 64;
    const size_t rowbase = (size_t)b * T_;

    const ushort* Qg = QK;
    const ushort* Kg = QK + 1024;
    const size_t vtbase = ((size_t)b * E_ + hoff) * T_;

    const int lr  = lane >> 3;
    const int jsw = ((lane & 7) ^ lr) * 8;

    const size_t qrow = (rowbase + q0 + wave * 16 + l15) * 2048 + hoff;
    s16x8 aq0 = *(const s16x8*)&Qg[qrow + quad * 8];
    s16x8 aq1 = *(const s16x8*)&Qg[qrow + 32 + quad * 8];

    const int kaoff0 = l15 * 64 + SWZ(quad,     l15);
    const int kaoff1 = l15 * 64 + SWZ(4 + quad, l15);
    ushort* myPt = &Pt[wave][0];

    const f32x4 zf = {0.f, 0.f, 0.f, 0.f};
    f32x4 o0[4] = {zf, zf, zf, zf};
    f32x4 o1[4] = {zf, zf, zf, zf};
    float lsum0 = 0.f, lsum1 = 0.f;

    #pragma unroll
    for (int p = 0; p < 2; ++p) {
        int r = wave * 16 + p * 8;
        gl_lds16(&Kg[(rowbase + r + lr) * 2048 + hoff + jsw], &Ks[0][r * 64]);
        gl_lds16(&Vt[vtbase + (size_t)(r + lr) * T_ + jsw],   &Vts[0][r * 64]);
    }
    __syncthreads();

    for (int kt = 0; kt < 16; ++kt) {
        const int cur = kt & 1;
        const int nxt = cur ^ 1;
        {
            const int ktn = (kt + 1) & 15;
            #pragma unroll
            for (int p = 0; p < 2; ++p) {
                int r = wave * 16 + p * 8;
                gl_lds16(&Kg[(rowbase + ktn * 64 + r + lr) * 2048 + hoff + jsw],
                         &Ks[nxt][r * 64]);
                gl_lds16(&Vt[vtbase + (size_t)(r + lr) * T_ + ktn * 64 + jsw],
                         &Vts[nxt][r * 64]);
            }
        }

        s16x8 va[4][2];
        #pragma unroll
        for (int jt = 0; jt < 4; ++jt) {
            va[jt][0] = *(const s16x8*)&Vts[cur][jt * 1024 + kaoff0];
            va[jt][1] = *(const s16x8*)&Vts[cur][jt * 1024 + kaoff1];
        }

        // ---- comp 0 ----
        {
            f32x4 S[4];
            #pragma unroll
            for (int jk = 0; jk < 4; ++jk) {
                s16x8 ka = *(const s16x8*)&Ks[cur][jk * 1024 + kaoff0];
                S[jk] = __builtin_amdgcn_mfma_f32_16x16x32_bf16(ka, aq0, zf, 0, 0, 0);
            }
            #pragma unroll
            for (int jk = 0; jk < 4; ++jk) {
                float e0 = exp2fast(S[jk][0]), e1 = exp2fast(S[jk][1]);
                float e2 = exp2fast(S[jk][2]), e3 = exp2fast(S[jk][3]);
                lsum0 += (e0 + e1) + (e2 + e3);
                uint2 pk; pk.x = f2bf2(e0, e1); pk.y = f2bf2(e2, e3);
                *(uint2*)&myPt[l15 * 64 + SWZ(2 * jk + (quad >> 1), l15) + (quad & 1) * 4] = pk;
            }
            #pragma unroll
            for (int h2 = 0; h2 < 2; ++h2) {
                s16x8 pf = *(const s16x8*)&myPt[h2 ? kaoff1 : kaoff0];
                #pragma unroll
                for (int jt = 0; jt < 4; ++jt)
                    o0[jt] = __builtin_amdgcn_mfma_f32_16x16x32_bf16(va[jt][h2], pf, o0[jt], 0, 0, 0);
            }
        }
        // ---- comp 1 ----
        {
            f32x4 S[4];
            #pragma unroll
            for (int jk = 0; jk < 4; ++jk) {
                s16x8 ka = *(const s16x8*)&Ks[cur][jk * 1024 + kaoff1];
                S[jk] = __builtin_amdgcn_mfma_f32_16x16x32_bf16(ka, aq1, zf, 0, 0, 0);
            }
            #pragma unroll
            for (int jk = 0; jk < 4; ++jk) {
                float e0 = exp2fast(S[jk][0]), e1 = exp2fast(S[jk][1]);
                float e2 = exp2fast(S[jk][2]), e3 = exp2fast(S[jk][3]);
                lsum1 += (e0 + e1) + (e2 + e3);
                uint2 pk; pk.x = f2bf2(e0, e1); pk.y = f2bf2(e2, e3);
                *(uint2*)&myPt[l15 * 64 + SWZ(2 * jk + (quad >> 1), l15) + (quad & 1) * 4] = pk;
            }
            #pragma unroll
            for (int h2 = 0; h2 < 2; ++h2) {
                s16x8 pf = *(const s16x8*)&myPt[h2 ? kaoff1 : kaoff0];
                #pragma unroll
                for (int jt = 0; jt < 4; ++jt)
                    o1[jt] = __builtin_amdgcn_mfma_f32_16x16x32_bf16(va[jt][h2], pf, o1[jt], 0, 0, 0);
            }
        }
        __syncthreads();
    }

    lsum0 += __shfl_xor(lsum0, 16); lsum0 += __shfl_xor(lsum0, 32);
    lsum1 += __shfl_xor(lsum1, 16); lsum1 += __shfl_xor(lsum1, 32);

    const float lam = lamp[0];
    const float fin = 1.f - LAMBDA_INIT;
    float i0 = 1.f / lsum0;
    float i1 = lam / lsum1;
    float val[4][4];
    float ssq = 0.f;
    #pragma unroll
    for (int jt = 0; jt < 4; ++jt)
        #pragma unroll
        for (int r = 0; r < 4; ++r) {
            float v = o0[jt][r] * i0 - o1[jt][r] * i1;
            val[jt][r] = v;
            ssq += v * v;
        }
    ssq += __shfl_xor(ssq, 16);
    ssq += __shfl_xor(ssq, 32);
    float sc = rsqrtf(ssq * (1.f / 64.f) + 1e-5f) * fin;
    size_t rowoff = (rowbase + q0 + wave * 16 + l15) * 1024 + hoff;
    #pragma unroll
    for (int jt = 0; jt < 4; ++jt) {
        float4 gv = *(const float4*)&g[jt * 16 + quad * 4];
        uint p01 = f2bf2(val[jt][0] * sc * gv.x, val[jt][1] * sc * gv.y);
        uint p23 = f2bf2(val[jt][2] * sc * gv.z, val[jt][3] * sc * gv.w);
        *(uint*)&O[rowoff + jt * 16 + quad * 4 + 0] = p01;
        *(uint*)&O[rowoff + jt * 16 + quad * 4 + 2] = p23;
    }
}

// ---------------------------------------------------------------------------
extern "C" void kernel_launch(void* const* d_in, const int* in_sizes, int n_in,
                              void* d_out, int out_size, void* d_ws, size_t ws_size,
                              hipStream_t stream)
{
    const float* x   = (const float*)d_in[0];
    const float* Wq  = (const float*)d_in[1];
    const float* Wk  = (const float*)d_in[2];
    const float* Wv  = (const float*)d_in[3];
    const float* Wo  = (const float*)d_in[4];
    const float* lq1 = (const float*)d_in[5];
    const float* lk1 = (const float*)d_in[6];
    const float* lq2 = (const float*)d_in[7];
    const float* lk2 = (const float*)d_in[8];
    const float* g   = (const float*)d_in[9];
    float* out = (float*)d_out;

    const int M = B_ * T_;                 // 4096
    const size_t ME = (size_t)M * E_;      // 4M elems
    const size_t EE = (size_t)E_ * E_;     // 1M elems
    ushort* xb  = (ushort*)d_ws;           // x bf16; later reused as Ab
    ushort* Wqb = xb  + ME;
    ushort* Wkb = Wqb + EE;
    ushort* Wvb = Wkb + EE;
    ushort* Wob = Wvb + EE;
    ushort* QK  = Wob + EE;                // [4096][2048] bf16
    ushort* Vtb = QK + (size_t)M * 2048;   // [4][1024][1024] bf16 (e-major)
    float*  lamp = (float*)(Vtb + ME);
    ushort* Ab  = xb;                      // aliases xb (dead after gemm_qkv)

    prep<<<4097, 256, 0, stream>>>(x, Wq, Wk, Wv, Wo, lq1, lk1, lq2, lk2,
                                   xb, Wqb, Wkb, Wvb, Wob, lamp);
    gemm_qkv<<<dim3(24, 32), 256, 0, stream>>>(xb, Wqb, Wkb, Wvb, QK, Vtb);
    diff_attn<<<B_ * H_ * (T_ / 64), 256, 0, stream>>>(QK, Vtb, g, lamp, Ab);
    gemm_out<<<dim3(16, 64), 256, 0, stream>>>(Ab, Wob, out);
}

// Round 8
// 188.664 us; speedup vs baseline: 1.1614x; 1.0266x over previous
//
#include <hip/hip_runtime.h>
#include <math.h>

#define E_   1024
#define H_   16
#define B_   4
#define T_   1024
#define LAMBDA_INIT 0.783605766532f
// D^-1/2 * log2(e): Q pre-scaled so softmax exp becomes raw v_exp_f32 (2^x)
#define SCALE_QL2E 0.25503486f

typedef short s16x8 __attribute__((ext_vector_type(8)));
typedef float f32x4 __attribute__((ext_vector_type(4)));

// ushort offset of 16B chunk c in a 64-ushort (128B) swizzled row r
#define SWZ(c, r) ((((c) ^ ((r) & 7)) * 8))

// float -> bf16 raw bits, round-to-nearest-even
__device__ inline ushort f2bf(float x) {
    unsigned u = __builtin_bit_cast(unsigned, x);
    u += 0x7fffu + ((u >> 16) & 1u);
    return (ushort)(u >> 16);
}

// pack two floats -> 2x bf16 in one uint (lo, hi)
__device__ inline uint f2bf2(float lo, float hi) {
#if __has_builtin(__builtin_amdgcn_cvt_pk_bf16_f32)
    typedef __bf16 bf16x2_t __attribute__((ext_vector_type(2)));
    bf16x2_t r = __builtin_amdgcn_cvt_pk_bf16_f32(lo, hi);
    return __builtin_bit_cast(uint, r);
#else
    uint ul = __builtin_bit_cast(uint, lo);
    uint uh = __builtin_bit_cast(uint, hi);
    ul += 0x7fffu + ((ul >> 16) & 1u);
    uh += 0x7fffu + ((uh >> 16) & 1u);
    return __builtin_amdgcn_perm(uh, ul, 0x07060302u);
#endif
}

// raw 2^x (v_exp_f32, no preceding v_mul)
__device__ inline float exp2fast(float x) {
#if __has_builtin(__builtin_amdgcn_exp2f)
    return __builtin_amdgcn_exp2f(x);
#else
    return exp2f(x);
#endif
}

// async global->LDS, 16 bytes per lane; LDS dest = base + lane*16
__device__ inline void gl_lds16(const ushort* g, ushort* l) {
    __builtin_amdgcn_global_load_lds((const __attribute__((address_space(1))) void*)g,
                                     (__attribute__((address_space(3))) void*)l,
                                     16, 0, 0);
}

// ---------------------------------------------------------------------------
// prep: fp32->bf16 casts for x + 4 weights, plus lambda scalar (one launch).
// ---------------------------------------------------------------------------
__global__ __launch_bounds__(256) void prep(
    const float* __restrict__ x,  const float* __restrict__ Wq,
    const float* __restrict__ Wk, const float* __restrict__ Wv,
    const float* __restrict__ Wo,
    const float* __restrict__ lq1, const float* __restrict__ lk1,
    const float* __restrict__ lq2, const float* __restrict__ lk2,
    ushort* __restrict__ xb, ushort* __restrict__ Wqb, ushort* __restrict__ Wkb,
    ushort* __restrict__ Wvb, ushort* __restrict__ Wob, float* __restrict__ lamp)
{
    const int blk = blockIdx.x;
    const int tid = threadIdx.x;
    if (blk >= 4096) {
        if (tid < 64) {
            float p1 = 0.f, p2 = 0.f;
            if (tid < 32) { p1 = lq1[tid] * lk1[tid]; p2 = lq2[tid] * lk2[tid]; }
            #pragma unroll
            for (int off = 32; off; off >>= 1) {
                p1 += __shfl_xor(p1, off);
                p2 += __shfl_xor(p2, off);
            }
            if (tid == 0) lamp[0] = expf(p1) - expf(p2) + LAMBDA_INIT;
        }
        return;
    }
    const float* in;
    ushort* out;
    int base;
    if (blk < 2048) { in = x; out = xb; base = blk; }
    else {
        int t = blk - 2048, w = t >> 9;
        base = t & 511;
        in  = w == 0 ? Wq  : (w == 1 ? Wk  : (w == 2 ? Wv  : Wo));
        out = w == 0 ? Wqb : (w == 1 ? Wkb : (w == 2 ? Wvb : Wob));
    }
    int i = (base * 256 + tid) * 8;
    float4 a = *(const float4*)&in[i];
    float4 b = *(const float4*)&in[i + 4];
    union { ushort u[8]; uint4 v; } o;
    o.u[0] = f2bf(a.x); o.u[1] = f2bf(a.y); o.u[2] = f2bf(a.z); o.u[3] = f2bf(a.w);
    o.u[4] = f2bf(b.x); o.u[5] = f2bf(b.y); o.u[6] = f2bf(b.z); o.u[7] = f2bf(b.w);
    *(uint4*)&out[i] = o.v;
}

// ---------------------------------------------------------------------------
// Fused QKV projection GEMM.
// R14: T4 counted-vmcnt pipeline on the R11 BK=64 body. LDS double-buffered
// (explicit unroll-by-2, STATIC buffer indices -> no R1-style addr recompute).
// Per step: issue 8 gl_lds for next tile -> asm vmcnt(8) (oldest 8 = current
// buffer complete; m135 oldest-first semantics) -> RAW s_barrier (no compiler
// vmcnt(0) drain) -> ds_read+MFMA -> raw barrier (WAR: buffer re-staged next
// step). Last step: vmcnt(0). LDS 64 KB -> 2 blocks/CU; latency now hidden
// intra-wave by the pipeline (compute/step ~2.6k cyc >> ~900 cyc load lat).
// Q/K accumulate TRANSPOSED (mfma(b,a)); V written transposed to Vt[b][e][t].
// ---------------------------------------------------------------------------
#define QKV_STAGE(NXTB, KN)                                                     \
    {                                                                           \
        _Pragma("unroll")                                                       \
        for (int p = 0; p < 4; ++p) {                                           \
            int r = wave * 32 + p * 8;                                          \
            gl_lds16(&Xb[(size_t)(bm + r + lr) * 1024 + (KN) + jsw], &As[NXTB][r * 64]); \
            gl_lds16(&W [(size_t)(wn + r + lr) * 1024 + (KN) + jsw], &Ws[NXTB][r * 64]); \
        }                                                                       \
    }

#define QKV_COMPUTE(CURB)                                                       \
    {                                                                           \
        _Pragma("unroll")                                                       \
        for (int ks = 0; ks < 2; ++ks) {                                        \
            const int roff = ks ? roff1 : roff0;                                \
            s16x8 a[4], b[4];                                                   \
            _Pragma("unroll")                                                   \
            for (int i = 0; i < 4; ++i)                                         \
                a[i] = *(const s16x8*)&As[CURB][(wr * 64 + i * 16) * 64 + roff];\
            _Pragma("unroll")                                                   \
            for (int j = 0; j < 4; ++j)                                         \
                b[j] = *(const s16x8*)&Ws[CURB][(wc * 64 + j * 16) * 64 + roff];\
            if (region < 2) {                                                   \
                _Pragma("unroll")                                               \
                for (int i = 0; i < 4; ++i)                                     \
                    _Pragma("unroll")                                           \
                    for (int j = 0; j < 4; ++j)                                 \
                        acc[i][j] = __builtin_amdgcn_mfma_f32_16x16x32_bf16(b[j], a[i], acc[i][j], 0, 0, 0); \
            } else {                                                            \
                _Pragma("unroll")                                               \
                for (int i = 0; i < 4; ++i)                                     \
                    _Pragma("unroll")                                           \
                    for (int j = 0; j < 4; ++j)                                 \
                        acc[i][j] = __builtin_amdgcn_mfma_f32_16x16x32_bf16(a[i], b[j], acc[i][j], 0, 0, 0); \
            }                                                                   \
        }                                                                       \
    }

#define QKV_STEP(CURB, NXTB, KT)                                                \
    {                                                                           \
        if ((KT) != 15) {                                                       \
            QKV_STAGE(NXTB, ((KT) + 1) * 64);                                   \
            asm volatile("s_waitcnt vmcnt(8)" ::: "memory");                    \
        } else {                                                                \
            asm volatile("s_waitcnt vmcnt(0)" ::: "memory");                    \
        }                                                                       \
        __builtin_amdgcn_s_barrier();                                           \
        QKV_COMPUTE(CURB);                                                      \
        if ((KT) != 15) __builtin_amdgcn_s_barrier();                           \
    }

__global__ __launch_bounds__(256) void gemm_qkv(
    const ushort* __restrict__ Xb, const ushort* __restrict__ Wqb,
    const ushort* __restrict__ Wkb, const ushort* __restrict__ Wvb,
    ushort* __restrict__ QK, ushort* __restrict__ Vt)
{
    __shared__ __align__(16) ushort As[2][128 * 64];   // 32 KB
    __shared__ __align__(16) ushort Ws[2][128 * 64];   // 32 KB
    const int tid = threadIdx.x;
    const int wave = tid >> 6, lane = tid & 63;
    const int l15 = lane & 15, quad = lane >> 4;
    const int bm = blockIdx.y * 128;
    const int bng = blockIdx.x * 128;
    const int region = bng >> 10;
    const ushort* W = region == 0 ? Wqb : (region == 1 ? Wkb : Wvb);
    const float scale = region == 0 ? SCALE_QL2E : 1.0f;
    const int wn = bng & 1023;
    const int lr  = lane >> 3;                 // row within 8-row staging group
    const int jsw = ((lane & 7) ^ lr) * 8;     // pre-swizzled global col chunk
    const int roff0 = l15 * 64 + SWZ(quad, l15);       // k-slice 0 (cols 0..31)
    const int roff1 = l15 * 64 + SWZ(4 + quad, l15);   // k-slice 1 (cols 32..63)

    f32x4 acc[4][4] = {};
    const int wr = wave >> 1, wc = wave & 1;

    // prologue: stage tile 0 into buffer 0 (readiness via step 0's vmcnt+barrier)
    QKV_STAGE(0, 0);

    for (int kt2 = 0; kt2 < 16; kt2 += 2) {
        QKV_STEP(0, 1, kt2);
        QKV_STEP(1, 0, kt2 + 1);
    }

    if (region < 2) {
        // lane holds: X-row = l15 (tile i), 4 consecutive cols quad*4+r (tile j)
        #pragma unroll
        for (int i = 0; i < 4; ++i) {
            int row = bm + wr * 64 + i * 16 + l15;
            #pragma unroll
            for (int j = 0; j < 4; ++j) {
                int col = region * 1024 + wn + wc * 64 + j * 16 + quad * 4;
                ushort4 o;
                o.x = f2bf(acc[i][j][0] * scale); o.y = f2bf(acc[i][j][1] * scale);
                o.z = f2bf(acc[i][j][2] * scale); o.w = f2bf(acc[i][j][3] * scale);
                *(ushort4*)&QK[(size_t)row * 2048 + col] = o;
            }
        }
    } else {
        // V: write transposed, Vt[b][e][t]; lane holds 4 consecutive t per (i,j)
        const int bb = bm >> 10;
        const int t0 = (bm & 1023) + wr * 64 + quad * 4;
        #pragma unroll
        for (int i = 0; i < 4; ++i)
            #pragma unroll
            for (int j = 0; j < 4; ++j) {
                int e = wn + wc * 64 + j * 16 + l15;
                ushort4 o;
                o.x = f2bf(acc[i][j][0]); o.y = f2bf(acc[i][j][1]);
                o.z = f2bf(acc[i][j][2]); o.w = f2bf(acc[i][j][3]);
                *(ushort4*)&Vt[((size_t)bb * E_ + e) * T_ + t0 + i * 16] = o;
            }
    }
}

// ---------------------------------------------------------------------------
// Output GEMM: R14 counted-vmcnt pipeline on the R13 64x64 geometry.
// Per step 4 gl_lds -> steady vmcnt(4). LDS 32 KB (grid-capped 4 blocks/CU).
// ---------------------------------------------------------------------------
#define OUT_STAGE(NXTB, KN)                                                     \
    {                                                                           \
        _Pragma("unroll")                                                       \
        for (int p = 0; p < 2; ++p) {                                           \
            int r = wave * 16 + p * 8;                                          \
            gl_lds16(&Ab[(size_t)(bm + r + lr) * 1024 + (KN) + jsw], &As[NXTB][r * 64]);  \
            gl_lds16(&Wob[(size_t)(bn + r + lr) * 1024 + (KN) + jsw], &Ws[NXTB][r * 64]); \
        }                                                                       \
    }

#define OUT_COMPUTE(CURB)                                                       \
    {                                                                           \
        _Pragma("unroll")                                                       \
        for (int ks = 0; ks < 2; ++ks) {                                        \
            const int roff = ks ? roff1 : roff0;                                \
            s16x8 a[2], b[2];                                                   \
            _Pragma("unroll")                                                   \
            for (int i = 0; i < 2; ++i)                                         \
                a[i] = *(const s16x8*)&As[CURB][(wr * 32 + i * 16) * 64 + roff];\
            _Pragma("unroll")                                                   \
            for (int j = 0; j < 2; ++j)                                         \
                b[j] = *(const s16x8*)&Ws[CURB][(wc * 32 + j * 16) * 64 + roff];\
            _Pragma("unroll")                                                   \
            for (int i = 0; i < 2; ++i)                                         \
                _Pragma("unroll")                                               \
                for (int j = 0; j < 2; ++j)                                     \
                    acc[i][j] = __builtin_amdgcn_mfma_f32_16x16x32_bf16(b[j], a[i], acc[i][j], 0, 0, 0); \
        }                                                                       \
    }

#define OUT_STEP(CURB, NXTB, KT)                                                \
    {                                                                           \
        if ((KT) != 15) {                                                       \
            OUT_STAGE(NXTB, ((KT) + 1) * 64);                                   \
            asm volatile("s_waitcnt vmcnt(4)" ::: "memory");                    \
        } else {                                                                \
            asm volatile("s_waitcnt vmcnt(0)" ::: "memory");                    \
        }                                                                       \
        __builtin_amdgcn_s_barrier();                                           \
        OUT_COMPUTE(CURB);                                                      \
        if ((KT) != 15) __builtin_amdgcn_s_barrier();                           \
    }

__global__ __launch_bounds__(256) void gemm_out(
    const ushort* __restrict__ Ab, const ushort* __restrict__ Wob,
    float* __restrict__ C)
{
    __shared__ __align__(16) ushort As[2][64 * 64];    // 16 KB
    __shared__ __align__(16) ushort Ws[2][64 * 64];    // 16 KB
    const int tid = threadIdx.x;
    const int wave = tid >> 6, lane = tid & 63;
    const int l15 = lane & 15, quad = lane >> 4;
    const int bm = blockIdx.y * 64;
    const int bn = blockIdx.x * 64;
    const int lr  = lane >> 3;
    const int jsw = ((lane & 7) ^ lr) * 8;
    const int roff0 = l15 * 64 + SWZ(quad, l15);
    const int roff1 = l15 * 64 + SWZ(4 + quad, l15);

    f32x4 acc[2][2] = {};
    const int wr = wave >> 1, wc = wave & 1;

    OUT_STAGE(0, 0);

    for (int kt2 = 0; kt2 < 16; kt2 += 2) {
        OUT_STEP(0, 1, kt2);
        OUT_STEP(1, 0, kt2 + 1);
    }

    // lane holds: A-row = l15 (tile i), 4 consecutive cols quad*4+r (tile j)
    #pragma unroll
    for (int i = 0; i < 2; ++i) {
        int row = bm + wr * 32 + i * 16 + l15;
        #pragma unroll
        for (int j = 0; j < 2; ++j) {
            int col = bn + wc * 32 + j * 16 + quad * 4;
            float4 o;
            o.x = acc[i][j][0]; o.y = acc[i][j][1];
            o.z = acc[i][j][2]; o.w = acc[i][j][3];
            *(float4*)&C[(size_t)row * 1024 + col] = o;
        }
    }
}

// ---------------------------------------------------------------------------
// Differential attention v6 — R4-exact (50.5-52.4 µs measured), unchanged.
// Its single barrier drains loads issued a full body (~7.5k cyc) earlier ->
// no exposed latency; counted-vmcnt not needed here.
// ---------------------------------------------------------------------------
__global__ __launch_bounds__(256, 4) void diff_attn(
    const ushort* __restrict__ QK, const ushort* __restrict__ Vt,
    const float* __restrict__ g, const float* __restrict__ lamp,
    ushort* __restrict__ O)
{
    __shared__ __align__(16) ushort Ks[2][4096];   // 16 KB
    __shared__ __align__(16) ushort Vts[2][4096];  // 16 KB
    __shared__ __align__(16) ushort Pt[4][1024];   //  8 KB

    const int tid  = threadIdx.x;
    const int lane = tid & 63;
    const int wave = tid >> 6;
    const int l15  = lane & 15;
    const int quad = lane >> 4;

    const int blk = blockIdx.x;
    const int bh = blk & 63;           // same-head blocks share blk%8 -> same XCD
    const int qt = blk >> 6;
    const int b  = bh >> 4;
    const int h  = bh & 15;
    const int q0 = qt * 64;
    const int hoff = h * 64;
    const size_t rowbase = (size_t)b * T_;

    const ushort* Qg = QK;
    const ushort* Kg = QK + 1024;
    const size_t vtbase = ((size_t)b * E_ + hoff) * T_;

    const int lr  = lane >> 3;
    const int jsw = ((lane & 7) ^ lr) * 8;

    const size_t qrow = (rowbase + q0 + wave * 16 + l15) * 2048 + hoff;
    s16x8 aq0 = *(const s16x8*)&Qg[qrow + quad * 8];
    s16x8 aq1 = *(const s16x8*)&Qg[qrow + 32 + quad * 8];

    const int kaoff0 = l15 * 64 + SWZ(quad,     l15);
    const int kaoff1 = l15 * 64 + SWZ(4 + quad, l15);
    ushort* myPt = &Pt[wave][0];

    const f32x4 zf = {0.f, 0.f, 0.f, 0.f};
    f32x4 o0[4] = {zf, zf, zf, zf};
    f32x4 o1[4] = {zf, zf, zf, zf};
    float lsum0 = 0.f, lsum1 = 0.f;

    #pragma unroll
    for (int p = 0; p < 2; ++p) {
        int r = wave * 16 + p * 8;
        gl_lds16(&Kg[(rowbase + r + lr) * 2048 + hoff + jsw], &Ks[0][r * 64]);
        gl_lds16(&Vt[vtbase + (size_t)(r + lr) * T_ + jsw],   &Vts[0][r * 64]);
    }
    __syncthreads();

    for (int kt = 0; kt < 16; ++kt) {
        const int cur = kt & 1;
        const int nxt = cur ^ 1;
        {
            const int ktn = (kt + 1) & 15;
            #pragma unroll
            for (int p = 0; p < 2; ++p) {
                int r = wave * 16 + p * 8;
                gl_lds16(&Kg[(rowbase + ktn * 64 + r + lr) * 2048 + hoff + jsw],
                         &Ks[nxt][r * 64]);
                gl_lds16(&Vt[vtbase + (size_t)(r + lr) * T_ + ktn * 64 + jsw],
                         &Vts[nxt][r * 64]);
            }
        }

        s16x8 va[4][2];
        #pragma unroll
        for (int jt = 0; jt < 4; ++jt) {
            va[jt][0] = *(const s16x8*)&Vts[cur][jt * 1024 + kaoff0];
            va[jt][1] = *(const s16x8*)&Vts[cur][jt * 1024 + kaoff1];
        }

        // ---- comp 0 ----
        {
            f32x4 S[4];
            #pragma unroll
            for (int jk = 0; jk < 4; ++jk) {
                s16x8 ka = *(const s16x8*)&Ks[cur][jk * 1024 + kaoff0];
                S[jk] = __builtin_amdgcn_mfma_f32_16x16x32_bf16(ka, aq0, zf, 0, 0, 0);
            }
            #pragma unroll
            for (int jk = 0; jk < 4; ++jk) {
                float e0 = exp2fast(S[jk][0]), e1 = exp2fast(S[jk][1]);
                float e2 = exp2fast(S[jk][2]), e3 = exp2fast(S[jk][3]);
                lsum0 += (e0 + e1) + (e2 + e3);
                uint2 pk; pk.x = f2bf2(e0, e1); pk.y = f2bf2(e2, e3);
                *(uint2*)&myPt[l15 * 64 + SWZ(2 * jk + (quad >> 1), l15) + (quad & 1) * 4] = pk;
            }
            #pragma unroll
            for (int h2 = 0; h2 < 2; ++h2) {
                s16x8 pf = *(const s16x8*)&myPt[h2 ? kaoff1 : kaoff0];
                #pragma unroll
                for (int jt = 0; jt < 4; ++jt)
                    o0[jt] = __builtin_amdgcn_mfma_f32_16x16x32_bf16(va[jt][h2], pf, o0[jt], 0, 0, 0);
            }
        }
        // ---- comp 1 ----
        {
            f32x4 S[4];
            #pragma unroll
            for (int jk = 0; jk < 4; ++jk) {
                s16x8 ka = *(const s16x8*)&Ks[cur][jk * 1024 + kaoff1];
                S[jk] = __builtin_amdgcn_mfma_f32_16x16x32_bf16(ka, aq1, zf, 0, 0, 0);
            }
            #pragma unroll
            for (int jk = 0; jk < 4; ++jk) {
                float e0 = exp2fast(S[jk][0]), e1 = exp2fast(S[jk][1]);
                float e2 = exp2fast(S[jk][2]), e3 = exp2fast(S[jk][3]);
                lsum1 += (e0 + e1) + (e2 + e3);
                uint2 pk; pk.x = f2bf2(e0, e1); pk.y = f2bf2(e2, e3);
                *(uint2*)&myPt[l15 * 64 + SWZ(2 * jk + (quad >> 1), l15) + (quad & 1) * 4] = pk;
            }
            #pragma unroll
            for (int h2 = 0; h2 < 2; ++h2) {
                s16x8 pf = *(const s16x8*)&myPt[h2 ? kaoff1 : kaoff0];
                #pragma unroll
                for (int jt = 0; jt < 4; ++jt)
                    o1[jt] = __builtin_amdgcn_mfma_f32_16x16x32_bf16(va[jt][h2], pf, o1[jt], 0, 0, 0);
            }
        }
        __syncthreads();
    }

    lsum0 += __shfl_xor(lsum0, 16); lsum0 += __shfl_xor(lsum0, 32);
    lsum1 += __shfl_xor(lsum1, 16); lsum1 += __shfl_xor(lsum1, 32);

    const float lam = lamp[0];
    const float fin = 1.f - LAMBDA_INIT;
    float i0 = 1.f / lsum0;
    float i1 = lam / lsum1;
    float val[4][4];
    float ssq = 0.f;
    #pragma unroll
    for (int jt = 0; jt < 4; ++jt)
        #pragma unroll
        for (int r = 0; r < 4; ++r) {
            float v = o0[jt][r] * i0 - o1[jt][r] * i1;
            val[jt][r] = v;
            ssq += v * v;
        }
    ssq += __shfl_xor(ssq, 16);
    ssq += __shfl_xor(ssq, 32);
    float sc = rsqrtf(ssq * (1.f / 64.f) + 1e-5f) * fin;
    size_t rowoff = (rowbase + q0 + wave * 16 + l15) * 1024 + hoff;
    #pragma unroll
    for (int jt = 0; jt < 4; ++jt) {
        float4 gv = *(const float4*)&g[jt * 16 + quad * 4];
        uint p01 = f2bf2(val[jt][0] * sc * gv.x, val[jt][1] * sc * gv.y);
        uint p23 = f2bf2(val[jt][2] * sc * gv.z, val[jt][3] * sc * gv.w);
        *(uint*)&O[rowoff + jt * 16 + quad * 4 + 0] = p01;
        *(uint*)&O[rowoff + jt * 16 + quad * 4 + 2] = p23;
    }
}

// ---------------------------------------------------------------------------
extern "C" void kernel_launch(void* const* d_in, const int* in_sizes, int n_in,
                              void* d_out, int out_size, void* d_ws, size_t ws_size,
                              hipStream_t stream)
{
    const float* x   = (const float*)d_in[0];
    const float* Wq  = (const float*)d_in[1];
    const float* Wk  = (const float*)d_in[2];
    const float* Wv  = (const float*)d_in[3];
    const float* Wo  = (const float*)d_in[4];
    const float* lq1 = (const float*)d_in[5];
    const float* lk1 = (const float*)d_in[6];
    const float* lq2 = (const float*)d_in[7];
    const float* lk2 = (const float*)d_in[8];
    const float* g   = (const float*)d_in[9];
    float* out = (float*)d_out;

    const int M = B_ * T_;                 // 4096
    const size_t ME = (size_t)M * E_;      // 4M elems
    const size_t EE = (size_t)E_ * E_;     // 1M elems
    ushort* xb  = (ushort*)d_ws;           // x bf16; later reused as Ab
    ushort* Wqb = xb  + ME;
    ushort* Wkb = Wqb + EE;
    ushort* Wvb = Wkb + EE;
    ushort* Wob = Wvb + EE;
    ushort* QK  = Wob + EE;                // [4096][2048] bf16
    ushort* Vtb = QK + (size_t)M * 2048;   // [4][1024][1024] bf16 (e-major)
    float*  lamp = (float*)(Vtb + ME);
    ushort* Ab  = xb;                      // aliases xb (dead after gemm_qkv)

    prep<<<4097, 256, 0, stream>>>(x, Wq, Wk, Wv, Wo, lq1, lk1, lq2, lk2,
                                   xb, Wqb, Wkb, Wvb, Wob, lamp);
    gemm_qkv<<<dim3(24, 32), 256, 0, stream>>>(xb, Wqb, Wkb, Wvb, QK, Vtb);
    diff_attn<<<B_ * H_ * (T_ / 64), 256, 0, stream>>>(QK, Vtb, g, lamp, Ab);
    gemm_out<<<dim3(16, 64), 256, 0, stream>>>(Ab, Wob, out);
}